// Round 6
// baseline (86.324 us; speedup 1.0000x reference)
//
#include <hip/hip_runtime.h>

#define P   13
#define BLK 512
#define NH  (P * 64)

typedef float2 c2;

__device__ __forceinline__ c2 cmul2(c2 a, c2 b) {
    return make_float2(a.x * b.x - a.y * b.y, a.x * b.y + a.y * b.x);
}
__device__ __forceinline__ c2 cfma2(c2 a, c2 b, c2 c) {  // a*b + c
    return make_float2(fmaf(a.x, b.x, fmaf(-a.y, b.y, c.x)),
                       fmaf(a.x, b.y, fmaf( a.y, b.x, c.y)));
}
__device__ __forceinline__ c2 shflx2(c2 v, int m) {
    c2 r; r.x = __shfl_xor(v.x, m, 64); r.y = __shfl_xor(v.y, m, 64); return r;
}

// ---------------- GF(2) frame tracking (compile-time verified) -------------
// Physical address p = (tid<<4)|r, 13 bits. Logical index bit b = parity(rowF[b]&p).
// CNOT(c,t) [bits bc=12-c, bt=12-t]: rowF[bt]^=rowF[bc]; colG[bc]^=colG[bt].
// F0 chosen so after one ring-CNOT chain every gate mask colG1[b] is a SINGLE
// physical bit: phi(0)=10, phi(1)=11, phi(k)=k-2 (k=2..11), phi(12)=12.
struct RowSet { unsigned r[13]; };
constexpr RowSet chain_rows(RowSet f) {
    for (int i = 0; i < 13; ++i) { int bc = 12 - i; int bt = (i == 12) ? 12 : (11 - i); f.r[bt] ^= f.r[bc]; }
    return f;
}
constexpr RowSet chain_cols(RowSet g) {
    for (int i = 0; i < 13; ++i) { int bc = 12 - i; int bt = (i == 12) ? 12 : (11 - i); g.r[bc] ^= g.r[bt]; }
    return g;
}
constexpr RowSet R0c {{0x0C00,0x0801,0x0003,0x0006,0x000C,0x0018,0x0030,0x0060,0x00C0,0x0180,0x0300,0x1600,0x1400}};
constexpr RowSet G0c {{0x1400,0x1C00,0x1C01,0x1C03,0x1C07,0x1C0F,0x1C1F,0x1C3F,0x1C7F,0x1CFF,0x1DFF,0x1FFF,0x0FFF}};
constexpr RowSet F1c = chain_rows(R0c);
constexpr RowSet F2c = chain_rows(F1c);
constexpr RowSet G1c = chain_cols(G0c);
static_assert(G1c.r[0]==0x0400 && G1c.r[1]==0x0800 && G1c.r[2]==0x0001 && G1c.r[3]==0x0002 &&
              G1c.r[4]==0x0004 && G1c.r[5]==0x0008 && G1c.r[6]==0x0010 && G1c.r[7]==0x0020 &&
              G1c.r[8]==0x0040 && G1c.r[9]==0x0080 && G1c.r[10]==0x0100 && G1c.r[11]==0x0200 &&
              G1c.r[12]==0x1000, "single-bit gate masks after chain 1");
static_assert(F1c.r[0]==0x0400 && F1c.r[1]==0x0800 && F1c.r[2]==0x0001 && F1c.r[12]==0x1000,
              "frame after chain 1 is the bit-permutation phi");

// V = RY(c)*RZ(b)*RY(a); u = {u00,u01,u10,u11}
__device__ __forceinline__ void build_V(float wa, float wb, float wc, c2* u) {
    float a = 0.5f * wa, b = 0.5f * wb, c = 0.5f * wc;
    float sa, ca, sb, cb, sc, cc;
    __sincosf(a, &sa, &ca); __sincosf(b, &sb, &cb); __sincosf(c, &sc, &cc);
    float A = ca * cb, Bq = ca * sb, C = sa * cb, D = sa * sb;
    u[0] = make_float2( cc * A - sc * C, -cc * Bq - sc * D);
    u[1] = make_float2(-cc * C - sc * A,  cc * D - sc * Bq);
    u[2] = make_float2( sc * A + cc * C, -sc * Bq + cc * D);
    u[3] = make_float2(-sc * C + cc * A,  sc * D + cc * Bq);
}

template<int K>
__device__ __forceinline__ void gate_reg(c2* s, const float* m) {
    c2 u00 = {m[0], m[1]}, u01 = {m[2], m[3]}, u10 = {m[4], m[5]}, u11 = {m[6], m[7]};
#pragma unroll
    for (int r = 0; r < 16; ++r)
        if (!(r & (1 << K))) {
            const int r1 = r | (1 << K);
            c2 a0 = s[r], a1 = s[r1];
            s[r]  = cfma2(u00, a0, cmul2(u01, a1));
            s[r1] = cfma2(u10, a0, cmul2(u11, a1));
        }
}

// Paired lane gates (tensor product of two commuting single-bit gates):
// 3 shuffles/reg instead of 4, same FLOPs.
template<int M1, int M2>
__device__ __forceinline__ void gate_lane2(c2* s, const float* mU, const float* mV, int lane) {
    c2 u00={mU[0],mU[1]}, u01={mU[2],mU[3]}, u10={mU[4],mU[5]}, u11={mU[6],mU[7]};
    c2 v00={mV[0],mV[1]}, v01={mV[2],mV[3]}, v10={mV[4],mV[5]}, v11={mV[6],mV[7]};
    int a = (lane & M1) ? 1 : 0, b = (lane & M2) ? 1 : 0;
    c2 Ud = a ? u11 : u00, Uo = a ? u10 : u01;
    c2 Vd = b ? v11 : v00, Vo = b ? v10 : v01;
    c2 wS = cmul2(Ud, Vd), w1 = cmul2(Uo, Vd), w2 = cmul2(Ud, Vo), w3 = cmul2(Uo, Vo);
#pragma unroll
    for (int r = 0; r < 16; ++r) {
        c2 p1 = shflx2(s[r], M1);
        c2 p2 = shflx2(s[r], M2);
        c2 p3 = shflx2(s[r], M1 | M2);
        c2 t = cmul2(wS, s[r]);
        t = cfma2(w1, p1, t);
        t = cfma2(w2, p2, t);
        s[r] = cfma2(w3, p3, t);
    }
}

__global__ __launch_bounds__(BLK) void qlc_kernel(
    const float* __restrict__ h, const float* __restrict__ enc_w,
    const float* __restrict__ enc_b, const float* __restrict__ qw,
    const float* __restrict__ dec_w, const float* __restrict__ alpha,
    float* __restrict__ out, int nlayers)
{
    const int n = blockIdx.x, tid = threadIdx.x, lane = tid & 63, wv = tid >> 6;
    __shared__ c2 plane[8192];            // 64 KB; multi-purpose
    float* smem = (float*)plane;
    float* vec  = smem;                   // [13*4]  per-wire 2-vectors (by logical bit)
    float* mats = smem + 64;              // [13*8]  layer-1 gate matrices (by wire)
    c2 s[16];

    // ---------------- Epilogue prefetch (hide HBM latency) ------------------
    const size_t rowoff = (size_t)n * NH;
    float h0 = h[rowoff + tid];
    float h1 = (tid < NH - 512) ? h[rowoff + 512 + tid] : 0.f;
    float dw = dec_w[tid & 63];
    float al = alpha[0];

    // ---------------- Phase 1: product state (encoding (+ layer-0)) --------
    for (int p = wv; p < P; p += 8) {
        float hv = h[rowoff + p * 64 + lane];
        float a0 = hv * enc_w[lane], a1 = hv * enc_w[64 + lane], a2 = hv * enc_w[128 + lane];
#pragma unroll
        for (int m = 32; m; m >>= 1) {
            a0 += __shfl_xor(a0, m, 64); a1 += __shfl_xor(a1, m, 64); a2 += __shfl_xor(a2, m, 64);
        }
        float x = 0.5f * (a0 + enc_b[0]), y = 0.5f * (a1 + enc_b[1]), z = 0.5f * (a2 + enc_b[2]);
        float sx, cx, sy, cy, sz, cz;
        __sincosf(x, &sx, &cx); __sincosf(y, &sy, &cy); __sincosf(z, &sz, &cz);
        c2 em = {cz, -sz}, ep = {cz, sz};
        c2 u0 = cmul2(em, make_float2(cy * cx,  sy * sx));   // col0 of RZ*RY*RX
        c2 u1 = cmul2(ep, make_float2(sy * cx, -cy * sx));
        c2 w0 = u0, w1 = u1;
        if (nlayers > 0) {
            c2 u[4]; const float* q = qw + p * 3;            // layer 0
            build_V(q[0], q[1], q[2], u);
            w0 = cfma2(u[0], u0, cmul2(u[1], u1));
            w1 = cfma2(u[2], u0, cmul2(u[3], u1));
        }
        if (lane == 0) {
            int b = 12 - p;
            vec[b*4+0] = w0.x; vec[b*4+1] = w0.y; vec[b*4+2] = w1.x; vec[b*4+3] = w1.y;
        }
    }
    if (nlayers == 2 && wv == 5 && lane < P) {               // layer-1 matrices (idle slot)
        c2 u[4]; const float* q = qw + (P + lane) * 3;
        build_V(q[0], q[1], q[2], u);
        float* m = mats + lane * 8;
        m[0]=u[0].x; m[1]=u[0].y; m[2]=u[1].x; m[3]=u[1].y;
        m[4]=u[2].x; m[5]=u[2].y; m[6]=u[3].x; m[7]=u[3].y;
    }
    __syncthreads();

    // Expansion: s[p] = prod_b vec[b][parity(R0[b]&p)]
    {
        c2 pref = {1.f, 0.f};
        const int UB[8] = {0, 6, 7, 8, 9, 10, 11, 12};       // r-independent bits
#pragma unroll
        for (int k = 0; k < 8; ++k) {
            const int b = UB[k];
            int t = __popc(tid & (R0c.r[b] >> 4)) & 1;
            c2 vv = { vec[b*4 + t*2], vec[b*4 + t*2 + 1] };
            pref = cmul2(pref, vv);
        }
        int t1 = (tid >> 7) & 1, t5 = tid & 1;               // R0[1]>>4=0x80, R0[5]>>4=1
        c2 w1v[2] = { {vec[4+t1*2], vec[5+t1*2]}, {vec[4+(t1^1)*2], vec[5+(t1^1)*2]} };
        c2 w2v[2] = { {vec[8],  vec[9]},  {vec[10], vec[11]} };
        c2 w3v[2] = { {vec[12], vec[13]}, {vec[14], vec[15]} };
        c2 w4v[2] = { {vec[16], vec[17]}, {vec[18], vec[19]} };
        c2 w5v[2] = { {vec[20+t5*2], vec[21+t5*2]}, {vec[20+(t5^1)*2], vec[21+(t5^1)*2]} };
        c2 v12[4], v34[4], P5[2];
        v12[0]=cmul2(w1v[0],w2v[0]); v12[1]=cmul2(w1v[0],w2v[1]);
        v12[2]=cmul2(w1v[1],w2v[0]); v12[3]=cmul2(w1v[1],w2v[1]);
        v34[0]=cmul2(w3v[0],w4v[0]); v34[1]=cmul2(w3v[0],w4v[1]);
        v34[2]=cmul2(w3v[1],w4v[0]); v34[3]=cmul2(w3v[1],w4v[1]);
        P5[0]=cmul2(pref,w5v[0]); P5[1]=cmul2(pref,w5v[1]);
#pragma unroll
        for (int r = 0; r < 16; ++r) {
            const int i12 = ((r & 1) << 1) | ((r ^ (r >> 1)) & 1);
            const int i34 = ((((r >> 1) ^ (r >> 2)) & 1) << 1) | (((r >> 2) ^ (r >> 3)) & 1);
            s[r] = cmul2(P5[(r >> 3) & 1], cmul2(v12[i12], v34[i34]));
        }
    }

    unsigned mrows[13];

    if (nlayers == 2) {
        // chain 1 is free (frame change). Layer-1 gates, all single-bit masks:
        gate_reg<0>(s, mats + 10*8);     // b=2  <- wire 10
        gate_reg<1>(s, mats +  9*8);     // b=3
        gate_reg<2>(s, mats +  8*8);     // b=4
        gate_reg<3>(s, mats +  7*8);     // b=5
        gate_lane2<1,  2>(s, mats + 6*8, mats + 5*8, lane);  // b=6,7
        gate_lane2<4,  8>(s, mats + 4*8, mats + 3*8, lane);  // b=8,9
        gate_lane2<16,32>(s, mats + 2*8, mats + 1*8, lane);  // b=10,11
        // LDS gates: preload matrices (mats region aliases plane)
        c2 umA[4], umB[4], umC[4];
#pragma unroll
        for (int j = 0; j < 4; ++j) {
            umA[j] = { mats[12*8 + j*2], mats[12*8 + j*2 + 1] };   // b=0  <- wire 12, tx=64
            umB[j] = { mats[11*8 + j*2], mats[11*8 + j*2 + 1] };   // b=1  <- wire 11, tx=128
            umC[j] = { mats[ 0*8 + j*2], mats[ 0*8 + j*2 + 1] };   // b=12 <- wire 0,  tx=256
        }
        __syncthreads();                 // vec/mats reads done before staging
        // trip 1: fused pair on tid bits 6,7 (tx 64,128)
#pragma unroll
        for (int r = 0; r < 16; ++r) plane[r*512 + tid] = s[r];
        __syncthreads();
        {
            int a = (tid >> 6) & 1, b = (tid >> 7) & 1;
            c2 Ud = a ? umA[3] : umA[0], Uo = a ? umA[2] : umA[1];
            c2 Vd = b ? umB[3] : umB[0], Vo = b ? umB[2] : umB[1];
            c2 wS = cmul2(Ud, Vd), w1 = cmul2(Uo, Vd), w2 = cmul2(Ud, Vo), w3 = cmul2(Uo, Vo);
            int p1 = tid ^ 64, p2 = tid ^ 128, p3 = tid ^ 192;
#pragma unroll
            for (int r = 0; r < 16; ++r) {
                c2 a1 = plane[r*512 + p1];
                c2 a2 = plane[r*512 + p2];
                c2 a3 = plane[r*512 + p3];
                c2 t = cmul2(wS, s[r]);
                t = cfma2(w1, a1, t);
                t = cfma2(w2, a2, t);
                s[r] = cfma2(w3, a3, t);
            }
        }
        __syncthreads();
        // trip 2: bit 8 (tx 256)
#pragma unroll
        for (int r = 0; r < 16; ++r) plane[r*512 + tid] = s[r];
        __syncthreads();
        {
            int mb = (tid >> 8) & 1;
            c2 ua = mb ? umC[3] : umC[0], ub = mb ? umC[2] : umC[1];
            int pt = tid ^ 256;
#pragma unroll
            for (int r = 0; r < 16; ++r) {
                c2 pv = plane[r*512 + pt];
                s[r] = cfma2(ua, s[r], cmul2(ub, pv));
            }
        }
        // chain 2 free; measurement rows are compile-time:
#pragma unroll
        for (int b = 0; b < 13; ++b) mrows[b] = F2c.r[b];
    } else {
        // -------- generic fallback (any nlayers != 2): staged gates --------
        unsigned rowF[13], colG[13];
#pragma unroll
        for (int b = 0; b < 13; ++b) { rowF[b] = R0c.r[b]; colG[b] = G0c.r[b]; }
        for (int l = 1; l < nlayers; ++l) {
#pragma unroll
            for (int i = 0; i < P; ++i) { int bc = 12-i, bt = (i==12)?12:(11-i); rowF[bt]^=rowF[bc]; colG[bc]^=colG[bt]; }
#pragma unroll
            for (int b = 0; b < 13; ++b) {
                const float* q = qw + ((size_t)l * P + (12 - b)) * 3;
                c2 u[4]; build_V(q[0], q[1], q[2], u);
                __syncthreads();
#pragma unroll
                for (int r = 0; r < 16; ++r) plane[r*512 + tid] = s[r];
                __syncthreads();
                unsigned m = colG[b], row = rowF[b];
                int pt = tid ^ (int)(m >> 4);
                unsigned mr = m & 15, rl = row & 15;
                int bt_ = __popc(tid & (row >> 4)) & 1;
#pragma unroll
                for (int r = 0; r < 16; ++r) {
                    c2 pv = plane[((r ^ mr) & 15) * 512 + pt];
                    int beta = bt_ ^ (__popc(r & rl) & 1);
                    c2 ua = beta ? u[3] : u[0], ub = beta ? u[2] : u[1];
                    s[r] = cfma2(ua, s[r], cmul2(ub, pv));
                }
            }
        }
        if (nlayers >= 1) {
#pragma unroll
            for (int i = 0; i < P; ++i) { int bc = 12-i, bt = (i==12)?12:(11-i); rowF[bt]^=rowF[bc]; colG[bc]^=colG[bt]; }
        }
#pragma unroll
        for (int b = 0; b < 13; ++b) mrows[b] = rowF[b];
    }

    // ---------------- Measure <Z_w> + decode --------------------------------
    float pr[16];
#pragma unroll
    for (int r = 0; r < 16; ++r) pr[r] = fmaf(s[r].x, s[r].x, s[r].y * s[r].y);
    float ev[13];
#pragma unroll
    for (int b = 0; b < 13; ++b) {
        unsigned row = mrows[b];
        int tp = __popc(tid & (row >> 4)) & 1;
        float acc = 0.f;
#pragma unroll
        for (int r = 0; r < 16; ++r)
            acc += (__popc((unsigned)r & row) & 1) ? -pr[r] : pr[r];
        ev[12 - b] = tp ? -acc : acc;    // wire w = 12-b
    }
#pragma unroll
    for (int w = 0; w < 13; ++w) {
#pragma unroll
        for (int m = 32; m; m >>= 1) ev[w] += __shfl_xor(ev[w], m, 64);
    }
    float* red  = smem + 256;
    float* red2 = smem + 384;
    __syncthreads();                     // all plane reads done; reuse LDS
    if (lane == 0) {
#pragma unroll
        for (int w = 0; w < 13; ++w) red[wv * 13 + w] = ev[w];
    }
    __syncthreads();
    if (tid < 13) {
        float sum = 0.f;
        for (int q = 0; q < 8; ++q) sum += red[q * 13 + tid];
        red2[tid] = sum;
    }
    __syncthreads();
    out[rowoff + tid] = fmaf(al * red2[wv], dw, h0);
    if (tid < NH - 512)
        out[rowoff + 512 + tid] = fmaf(al * red2[wv + 8], dw, h1);
}

extern "C" void kernel_launch(void* const* d_in, const int* in_sizes, int n_in,
                              void* d_out, int out_size, void* d_ws, size_t ws_size,
                              hipStream_t stream) {
    const float* h     = (const float*)d_in[0];
    const float* enc_w = (const float*)d_in[1];
    const float* enc_b = (const float*)d_in[2];
    const float* qw    = (const float*)d_in[3];
    const float* dec_w = (const float*)d_in[4];
    const float* alpha = (const float*)d_in[5];
    float* out = (float*)d_out;

    int N = in_sizes[0] / NH;          // B*T samples
    int L = in_sizes[3] / (P * 3);     // variational layers

    qlc_kernel<<<N, BLK, 0, stream>>>(h, enc_w, enc_b, qw, dec_w, alpha, out, L);
}

// Round 7
// 79.981 us; speedup vs baseline: 1.0793x; 1.0793x over previous
//
#include <hip/hip_runtime.h>

#define P   13
#define BLK 512
#define NH  (P * 64)

typedef float2 c2;

__device__ __forceinline__ c2 cmul2(c2 a, c2 b) {
    return make_float2(a.x * b.x - a.y * b.y, a.x * b.y + a.y * b.x);
}
__device__ __forceinline__ c2 cfma2(c2 a, c2 b, c2 c) {  // a*b + c
    return make_float2(fmaf(a.x, b.x, fmaf(-a.y, b.y, c.x)),
                       fmaf(a.x, b.y, fmaf( a.y, b.x, c.y)));
}
__device__ __forceinline__ c2 shflx2(c2 v, int m) {
    c2 r; r.x = __shfl_xor(v.x, m, 64); r.y = __shfl_xor(v.y, m, 64); return r;
}

// ---------------- GF(2) frame tracking (compile-time verified) -------------
// Physical address p = (tid<<4)|r, 13 bits. Logical index bit b = parity(rowF[b]&p).
// CNOT(c,t) [bits bc=12-c, bt=12-t]: rowF[bt]^=rowF[bc]; colG[bc]^=colG[bt].
// F0 chosen so after one ring-CNOT chain every gate mask colG1[b] is a SINGLE
// physical bit: phi(0)=10, phi(1)=11, phi(k)=k-2 (k=2..11), phi(12)=12.
struct RowSet { unsigned r[13]; };
constexpr RowSet chain_rows(RowSet f) {
    for (int i = 0; i < 13; ++i) { int bc = 12 - i; int bt = (i == 12) ? 12 : (11 - i); f.r[bt] ^= f.r[bc]; }
    return f;
}
constexpr RowSet chain_cols(RowSet g) {
    for (int i = 0; i < 13; ++i) { int bc = 12 - i; int bt = (i == 12) ? 12 : (11 - i); g.r[bc] ^= g.r[bt]; }
    return g;
}
constexpr RowSet R0c {{0x0C00,0x0801,0x0003,0x0006,0x000C,0x0018,0x0030,0x0060,0x00C0,0x0180,0x0300,0x1600,0x1400}};
constexpr RowSet G0c {{0x1400,0x1C00,0x1C01,0x1C03,0x1C07,0x1C0F,0x1C1F,0x1C3F,0x1C7F,0x1CFF,0x1DFF,0x1FFF,0x0FFF}};
constexpr RowSet F1c = chain_rows(R0c);
constexpr RowSet F2c = chain_rows(F1c);
constexpr RowSet G1c = chain_cols(G0c);
static_assert(G1c.r[0]==0x0400 && G1c.r[1]==0x0800 && G1c.r[2]==0x0001 && G1c.r[3]==0x0002 &&
              G1c.r[4]==0x0004 && G1c.r[5]==0x0008 && G1c.r[6]==0x0010 && G1c.r[7]==0x0020 &&
              G1c.r[8]==0x0040 && G1c.r[9]==0x0080 && G1c.r[10]==0x0100 && G1c.r[11]==0x0200 &&
              G1c.r[12]==0x1000, "single-bit gate masks after chain 1");
static_assert(F1c.r[0]==0x0400 && F1c.r[1]==0x0800 && F1c.r[2]==0x0001 && F1c.r[12]==0x1000,
              "frame after chain 1 is the bit-permutation phi");

// V = RY(c)*RZ(b)*RY(a); u = {u00,u01,u10,u11}
__device__ __forceinline__ void build_V(float wa, float wb, float wc, c2* u) {
    float a = 0.5f * wa, b = 0.5f * wb, c = 0.5f * wc;
    float sa, ca, sb, cb, sc, cc;
    __sincosf(a, &sa, &ca); __sincosf(b, &sb, &cb); __sincosf(c, &sc, &cc);
    float A = ca * cb, Bq = ca * sb, C = sa * cb, D = sa * sb;
    u[0] = make_float2( cc * A - sc * C, -cc * Bq - sc * D);
    u[1] = make_float2(-cc * C - sc * A,  cc * D - sc * Bq);
    u[2] = make_float2( sc * A + cc * C, -sc * Bq + cc * D);
    u[3] = make_float2(-sc * C + cc * A,  sc * D + cc * Bq);
}

template<int K>
__device__ __forceinline__ void gate_reg(c2* s, const float* m) {
    c2 u00 = {m[0], m[1]}, u01 = {m[2], m[3]}, u10 = {m[4], m[5]}, u11 = {m[6], m[7]};
#pragma unroll
    for (int r = 0; r < 16; ++r)
        if (!(r & (1 << K))) {
            const int r1 = r | (1 << K);
            c2 a0 = s[r], a1 = s[r1];
            s[r]  = cfma2(u00, a0, cmul2(u01, a1));
            s[r1] = cfma2(u10, a0, cmul2(u11, a1));
        }
}

// Paired lane gates (tensor product of two commuting single-bit gates):
// 3 shuffles/reg instead of 4, same FLOPs.
template<int M1, int M2>
__device__ __forceinline__ void gate_lane2(c2* s, const float* mU, const float* mV, int lane) {
    c2 u00={mU[0],mU[1]}, u01={mU[2],mU[3]}, u10={mU[4],mU[5]}, u11={mU[6],mU[7]};
    c2 v00={mV[0],mV[1]}, v01={mV[2],mV[3]}, v10={mV[4],mV[5]}, v11={mV[6],mV[7]};
    int a = (lane & M1) ? 1 : 0, b = (lane & M2) ? 1 : 0;
    c2 Ud = a ? u11 : u00, Uo = a ? u10 : u01;
    c2 Vd = b ? v11 : v00, Vo = b ? v10 : v01;
    c2 wS = cmul2(Ud, Vd), w1 = cmul2(Uo, Vd), w2 = cmul2(Ud, Vo), w3 = cmul2(Uo, Vo);
#pragma unroll
    for (int r = 0; r < 16; ++r) {
        c2 p1 = shflx2(s[r], M1);
        c2 p2 = shflx2(s[r], M2);
        c2 p3 = shflx2(s[r], M1 | M2);
        c2 t = cmul2(wS, s[r]);
        t = cfma2(w1, p1, t);
        t = cfma2(w2, p2, t);
        s[r] = cfma2(w3, p3, t);
    }
}

// TWO=true: specialized nlayers==2 path (no generic machinery in the
// register allocation). __launch_bounds__(512,2): one 8-wave block/CU is
// 2 waves/EU, so allow up to 256 VGPRs -> no scratch spills (round-6
// counters showed 11 MB/dispatch spill writeback at the 128-VGPR cap).
template<bool TWO>
__global__ __launch_bounds__(BLK, 2) void qlc_kernel(
    const float* __restrict__ h, const float* __restrict__ enc_w,
    const float* __restrict__ enc_b, const float* __restrict__ qw,
    const float* __restrict__ dec_w, const float* __restrict__ alpha,
    float* __restrict__ out, int nlayers)
{
    const int n = blockIdx.x, tid = threadIdx.x, lane = tid & 63, wv = tid >> 6;
    __shared__ c2 plane[8192];            // 64 KB; multi-purpose
    float* smem = (float*)plane;
    float* vec  = smem;                   // [13*4]  per-wire 2-vectors (by logical bit)
    float* mats = smem + 64;              // [13*8]  layer-1 gate matrices (by wire)
    c2 s[16];

    // ---------------- Epilogue prefetch (hide HBM latency) ------------------
    const size_t rowoff = (size_t)n * NH;
    float h0 = h[rowoff + tid];
    float h1 = (tid < NH - 512) ? h[rowoff + 512 + tid] : 0.f;
    float dw = dec_w[tid & 63];
    float al = alpha[0];

    // ---------------- Phase 1: product state (encoding (+ layer-0)) --------
    for (int p = wv; p < P; p += 8) {
        float hv = h[rowoff + p * 64 + lane];
        float a0 = hv * enc_w[lane], a1 = hv * enc_w[64 + lane], a2 = hv * enc_w[128 + lane];
#pragma unroll
        for (int m = 32; m; m >>= 1) {
            a0 += __shfl_xor(a0, m, 64); a1 += __shfl_xor(a1, m, 64); a2 += __shfl_xor(a2, m, 64);
        }
        float x = 0.5f * (a0 + enc_b[0]), y = 0.5f * (a1 + enc_b[1]), z = 0.5f * (a2 + enc_b[2]);
        float sx, cx, sy, cy, sz, cz;
        __sincosf(x, &sx, &cx); __sincosf(y, &sy, &cy); __sincosf(z, &sz, &cz);
        c2 em = {cz, -sz}, ep = {cz, sz};
        c2 u0 = cmul2(em, make_float2(cy * cx,  sy * sx));   // col0 of RZ*RY*RX
        c2 u1 = cmul2(ep, make_float2(sy * cx, -cy * sx));
        c2 w0 = u0, w1 = u1;
        if (TWO || nlayers > 0) {
            c2 u[4]; const float* q = qw + p * 3;            // layer 0
            build_V(q[0], q[1], q[2], u);
            w0 = cfma2(u[0], u0, cmul2(u[1], u1));
            w1 = cfma2(u[2], u0, cmul2(u[3], u1));
        }
        if (lane == 0) {
            int b = 12 - p;
            vec[b*4+0] = w0.x; vec[b*4+1] = w0.y; vec[b*4+2] = w1.x; vec[b*4+3] = w1.y;
        }
    }
    if (TWO && wv == 5 && lane < P) {                        // layer-1 matrices (idle slot)
        c2 u[4]; const float* q = qw + (P + lane) * 3;
        build_V(q[0], q[1], q[2], u);
        float* m = mats + lane * 8;
        m[0]=u[0].x; m[1]=u[0].y; m[2]=u[1].x; m[3]=u[1].y;
        m[4]=u[2].x; m[5]=u[2].y; m[6]=u[3].x; m[7]=u[3].y;
    }
    __syncthreads();

    // Expansion: s[p] = prod_b vec[b][parity(R0[b]&p)]
    {
        c2 pref = {1.f, 0.f};
        const int UB[8] = {0, 6, 7, 8, 9, 10, 11, 12};       // r-independent bits
#pragma unroll
        for (int k = 0; k < 8; ++k) {
            const int b = UB[k];
            int t = __popc(tid & (R0c.r[b] >> 4)) & 1;
            c2 vv = { vec[b*4 + t*2], vec[b*4 + t*2 + 1] };
            pref = cmul2(pref, vv);
        }
        int t1 = (tid >> 7) & 1, t5 = tid & 1;               // R0[1]>>4=0x80, R0[5]>>4=1
        c2 w1v[2] = { {vec[4+t1*2], vec[5+t1*2]}, {vec[4+(t1^1)*2], vec[5+(t1^1)*2]} };
        c2 w2v[2] = { {vec[8],  vec[9]},  {vec[10], vec[11]} };
        c2 w3v[2] = { {vec[12], vec[13]}, {vec[14], vec[15]} };
        c2 w4v[2] = { {vec[16], vec[17]}, {vec[18], vec[19]} };
        c2 w5v[2] = { {vec[20+t5*2], vec[21+t5*2]}, {vec[20+(t5^1)*2], vec[21+(t5^1)*2]} };
        c2 v12[4], v34[4], P5[2];
        v12[0]=cmul2(w1v[0],w2v[0]); v12[1]=cmul2(w1v[0],w2v[1]);
        v12[2]=cmul2(w1v[1],w2v[0]); v12[3]=cmul2(w1v[1],w2v[1]);
        v34[0]=cmul2(w3v[0],w4v[0]); v34[1]=cmul2(w3v[0],w4v[1]);
        v34[2]=cmul2(w3v[1],w4v[0]); v34[3]=cmul2(w3v[1],w4v[1]);
        P5[0]=cmul2(pref,w5v[0]); P5[1]=cmul2(pref,w5v[1]);
#pragma unroll
        for (int r = 0; r < 16; ++r) {
            const int i12 = ((r & 1) << 1) | ((r ^ (r >> 1)) & 1);
            const int i34 = ((((r >> 1) ^ (r >> 2)) & 1) << 1) | (((r >> 2) ^ (r >> 3)) & 1);
            s[r] = cmul2(P5[(r >> 3) & 1], cmul2(v12[i12], v34[i34]));
        }
    }

    unsigned mrows[13];

    if (TWO) {
        // chain 1 is free (frame change). Layer-1 gates, all single-bit masks:
        gate_reg<0>(s, mats + 10*8);     // b=2  <- wire 10
        gate_reg<1>(s, mats +  9*8);     // b=3
        gate_reg<2>(s, mats +  8*8);     // b=4
        gate_reg<3>(s, mats +  7*8);     // b=5
        gate_lane2<1,  2>(s, mats + 6*8, mats + 5*8, lane);  // b=6,7
        gate_lane2<4,  8>(s, mats + 4*8, mats + 3*8, lane);  // b=8,9
        gate_lane2<16,32>(s, mats + 2*8, mats + 1*8, lane);  // b=10,11
        __syncthreads();                 // vec/mats reads done before staging
        // trip 1: fused pair on tid bits 6,7 (tx 64,128). Matrices rebuilt
        // HERE (wave-uniform qw loads) so nothing is held across staging.
#pragma unroll
        for (int r = 0; r < 16; ++r) plane[r*512 + tid] = s[r];
        {
            c2 uA[4], uB[4];
            const float* qA = qw + (P + 12) * 3;   // b=0  <- wire 12, tx=64
            const float* qB = qw + (P + 11) * 3;   // b=1  <- wire 11, tx=128
            build_V(qA[0], qA[1], qA[2], uA);
            build_V(qB[0], qB[1], qB[2], uB);
            int a = (tid >> 6) & 1, b = (tid >> 7) & 1;
            c2 Ud = a ? uA[3] : uA[0], Uo = a ? uA[2] : uA[1];
            c2 Vd = b ? uB[3] : uB[0], Vo = b ? uB[2] : uB[1];
            c2 wS = cmul2(Ud, Vd), w1 = cmul2(Uo, Vd), w2 = cmul2(Ud, Vo), w3 = cmul2(Uo, Vo);
            int p1 = tid ^ 64, p2 = tid ^ 128, p3 = tid ^ 192;
            __syncthreads();
#pragma unroll
            for (int r = 0; r < 16; ++r) {
                c2 a1 = plane[r*512 + p1];
                c2 a2 = plane[r*512 + p2];
                c2 a3 = plane[r*512 + p3];
                c2 t = cmul2(wS, s[r]);
                t = cfma2(w1, a1, t);
                t = cfma2(w2, a2, t);
                s[r] = cfma2(w3, a3, t);
            }
        }
        __syncthreads();
        // trip 2: bit 8 (tx 256)
#pragma unroll
        for (int r = 0; r < 16; ++r) plane[r*512 + tid] = s[r];
        {
            c2 uC[4];
            const float* qC = qw + (P + 0) * 3;    // b=12 <- wire 0, tx=256
            build_V(qC[0], qC[1], qC[2], uC);
            int mb = (tid >> 8) & 1;
            c2 ua = mb ? uC[3] : uC[0], ub = mb ? uC[2] : uC[1];
            int pt = tid ^ 256;
            __syncthreads();
#pragma unroll
            for (int r = 0; r < 16; ++r) {
                c2 pv = plane[r*512 + pt];
                s[r] = cfma2(ua, s[r], cmul2(ub, pv));
            }
        }
        // chain 2 free; measurement rows are compile-time:
#pragma unroll
        for (int b = 0; b < 13; ++b) mrows[b] = F2c.r[b];
    } else {
        // -------- generic fallback (any nlayers != 2): staged gates --------
        unsigned rowF[13], colG[13];
#pragma unroll
        for (int b = 0; b < 13; ++b) { rowF[b] = R0c.r[b]; colG[b] = G0c.r[b]; }
        for (int l = 1; l < nlayers; ++l) {
#pragma unroll
            for (int i = 0; i < P; ++i) { int bc = 12-i, bt = (i==12)?12:(11-i); rowF[bt]^=rowF[bc]; colG[bc]^=colG[bt]; }
#pragma unroll
            for (int b = 0; b < 13; ++b) {
                const float* q = qw + ((size_t)l * P + (12 - b)) * 3;
                c2 u[4]; build_V(q[0], q[1], q[2], u);
                __syncthreads();
#pragma unroll
                for (int r = 0; r < 16; ++r) plane[r*512 + tid] = s[r];
                __syncthreads();
                unsigned m = colG[b], row = rowF[b];
                int pt = tid ^ (int)(m >> 4);
                unsigned mr = m & 15, rl = row & 15;
                int bt_ = __popc(tid & (row >> 4)) & 1;
#pragma unroll
                for (int r = 0; r < 16; ++r) {
                    c2 pv = plane[((r ^ mr) & 15) * 512 + pt];
                    int beta = bt_ ^ (__popc(r & rl) & 1);
                    c2 ua = beta ? u[3] : u[0], ub = beta ? u[2] : u[1];
                    s[r] = cfma2(ua, s[r], cmul2(ub, pv));
                }
            }
        }
        if (nlayers >= 1) {
#pragma unroll
            for (int i = 0; i < P; ++i) { int bc = 12-i, bt = (i==12)?12:(11-i); rowF[bt]^=rowF[bc]; colG[bc]^=colG[bt]; }
        }
#pragma unroll
        for (int b = 0; b < 13; ++b) mrows[b] = rowF[b];
    }

    // ---------------- Measure <Z_w> + decode --------------------------------
    float pr[16];
#pragma unroll
    for (int r = 0; r < 16; ++r) pr[r] = fmaf(s[r].x, s[r].x, s[r].y * s[r].y);
    float ev[13];
#pragma unroll
    for (int b = 0; b < 13; ++b) {
        unsigned row = mrows[b];
        int tp = __popc(tid & (row >> 4)) & 1;
        float acc = 0.f;
#pragma unroll
        for (int r = 0; r < 16; ++r)
            acc += (__popc((unsigned)r & row) & 1) ? -pr[r] : pr[r];
        ev[12 - b] = tp ? -acc : acc;    // wire w = 12-b
    }
#pragma unroll
    for (int w = 0; w < 13; ++w) {
#pragma unroll
        for (int m = 32; m; m >>= 1) ev[w] += __shfl_xor(ev[w], m, 64);
    }
    float* red  = smem + 256;
    float* red2 = smem + 384;
    __syncthreads();                     // all plane reads done; reuse LDS
    if (lane == 0) {
#pragma unroll
        for (int w = 0; w < 13; ++w) red[wv * 13 + w] = ev[w];
    }
    __syncthreads();
    if (tid < 13) {
        float sum = 0.f;
        for (int q = 0; q < 8; ++q) sum += red[q * 13 + tid];
        red2[tid] = sum;
    }
    __syncthreads();
    out[rowoff + tid] = fmaf(al * red2[wv], dw, h0);
    if (tid < NH - 512)
        out[rowoff + 512 + tid] = fmaf(al * red2[wv + 8], dw, h1);
}

extern "C" void kernel_launch(void* const* d_in, const int* in_sizes, int n_in,
                              void* d_out, int out_size, void* d_ws, size_t ws_size,
                              hipStream_t stream) {
    const float* h     = (const float*)d_in[0];
    const float* enc_w = (const float*)d_in[1];
    const float* enc_b = (const float*)d_in[2];
    const float* qw    = (const float*)d_in[3];
    const float* dec_w = (const float*)d_in[4];
    const float* alpha = (const float*)d_in[5];
    float* out = (float*)d_out;

    int N = in_sizes[0] / NH;          // B*T samples
    int L = in_sizes[3] / (P * 3);     // variational layers

    if (L == 2)
        qlc_kernel<true><<<N, BLK, 0, stream>>>(h, enc_w, enc_b, qw, dec_w, alpha, out, L);
    else
        qlc_kernel<false><<<N, BLK, 0, stream>>>(h, enc_w, enc_b, qw, dec_w, alpha, out, L);
}

// Round 8
// 79.242 us; speedup vs baseline: 1.0894x; 1.0093x over previous
//
#include <hip/hip_runtime.h>

#define P   13
#define BLK 512
#define NH  (P * 64)

typedef float2 c2;

__device__ __forceinline__ c2 cmul2(c2 a, c2 b) {
    return make_float2(a.x * b.x - a.y * b.y, a.x * b.y + a.y * b.x);
}
__device__ __forceinline__ c2 cfma2(c2 a, c2 b, c2 c) {  // a*b + c
    return make_float2(fmaf(a.x, b.x, fmaf(-a.y, b.y, c.x)),
                       fmaf(a.x, b.y, fmaf( a.y, b.x, c.y)));
}
__device__ __forceinline__ c2 shflx2(c2 v, int m) {
    c2 r; r.x = __shfl_xor(v.x, m, 64); r.y = __shfl_xor(v.y, m, 64); return r;
}

// ---------------- GF(2) frame tracking (compile-time verified) -------------
// Physical address p = (tid<<4)|r, 13 bits. Logical index bit b = parity(rowF[b]&p).
// CNOT(c,t) [bits bc=12-c, bt=12-t]: rowF[bt]^=rowF[bc]; colG[bc]^=colG[bt].
// F0 chosen so after one ring-CNOT chain every gate mask colG1[b] is a SINGLE
// physical bit: phi(0)=10, phi(1)=11, phi(k)=k-2 (k=2..11), phi(12)=12.
struct RowSet { unsigned r[13]; };
constexpr RowSet chain_rows(RowSet f) {
    for (int i = 0; i < 13; ++i) { int bc = 12 - i; int bt = (i == 12) ? 12 : (11 - i); f.r[bt] ^= f.r[bc]; }
    return f;
}
constexpr RowSet chain_cols(RowSet g) {
    for (int i = 0; i < 13; ++i) { int bc = 12 - i; int bt = (i == 12) ? 12 : (11 - i); g.r[bc] ^= g.r[bt]; }
    return g;
}
constexpr RowSet R0c {{0x0C00,0x0801,0x0003,0x0006,0x000C,0x0018,0x0030,0x0060,0x00C0,0x0180,0x0300,0x1600,0x1400}};
constexpr RowSet G0c {{0x1400,0x1C00,0x1C01,0x1C03,0x1C07,0x1C0F,0x1C1F,0x1C3F,0x1C7F,0x1CFF,0x1DFF,0x1FFF,0x0FFF}};
constexpr RowSet F1c = chain_rows(R0c);
constexpr RowSet F2c = chain_rows(F1c);
constexpr RowSet G1c = chain_cols(G0c);
static_assert(G1c.r[0]==0x0400 && G1c.r[1]==0x0800 && G1c.r[2]==0x0001 && G1c.r[3]==0x0002 &&
              G1c.r[4]==0x0004 && G1c.r[5]==0x0008 && G1c.r[6]==0x0010 && G1c.r[7]==0x0020 &&
              G1c.r[8]==0x0040 && G1c.r[9]==0x0080 && G1c.r[10]==0x0100 && G1c.r[11]==0x0200 &&
              G1c.r[12]==0x1000, "single-bit gate masks after chain 1");
static_assert(F1c.r[0]==0x0400 && F1c.r[1]==0x0800 && F1c.r[2]==0x0001 && F1c.r[12]==0x1000,
              "frame after chain 1 is the bit-permutation phi");

// V = RY(c)*RZ(b)*RY(a); u = {u00,u01,u10,u11}
__device__ __forceinline__ void build_V(float wa, float wb, float wc, c2* u) {
    float a = 0.5f * wa, b = 0.5f * wb, c = 0.5f * wc;
    float sa, ca, sb, cb, sc, cc;
    __sincosf(a, &sa, &ca); __sincosf(b, &sb, &cb); __sincosf(c, &sc, &cc);
    float A = ca * cb, Bq = ca * sb, C = sa * cb, D = sa * sb;
    u[0] = make_float2( cc * A - sc * C, -cc * Bq - sc * D);
    u[1] = make_float2(-cc * C - sc * A,  cc * D - sc * Bq);
    u[2] = make_float2( sc * A + cc * C, -sc * Bq + cc * D);
    u[3] = make_float2(-sc * C + cc * A,  sc * D + cc * Bq);
}

template<int K>
__device__ __forceinline__ void gate_reg(c2* s, const float* m) {
    c2 u00 = {m[0], m[1]}, u01 = {m[2], m[3]}, u10 = {m[4], m[5]}, u11 = {m[6], m[7]};
#pragma unroll
    for (int r = 0; r < 16; ++r)
        if (!(r & (1 << K))) {
            const int r1 = r | (1 << K);
            c2 a0 = s[r], a1 = s[r1];
            s[r]  = cfma2(u00, a0, cmul2(u01, a1));
            s[r1] = cfma2(u10, a0, cmul2(u11, a1));
        }
}

// Paired lane gates (tensor product of two commuting single-bit gates):
// 3 shuffles/reg instead of 4, same FLOPs.
template<int M1, int M2>
__device__ __forceinline__ void gate_lane2(c2* s, const float* mU, const float* mV, int lane) {
    c2 u00={mU[0],mU[1]}, u01={mU[2],mU[3]}, u10={mU[4],mU[5]}, u11={mU[6],mU[7]};
    c2 v00={mV[0],mV[1]}, v01={mV[2],mV[3]}, v10={mV[4],mV[5]}, v11={mV[6],mV[7]};
    int a = (lane & M1) ? 1 : 0, b = (lane & M2) ? 1 : 0;
    c2 Ud = a ? u11 : u00, Uo = a ? u10 : u01;
    c2 Vd = b ? v11 : v00, Vo = b ? v10 : v01;
    c2 wS = cmul2(Ud, Vd), w1 = cmul2(Uo, Vd), w2 = cmul2(Ud, Vo), w3 = cmul2(Uo, Vo);
#pragma unroll
    for (int r = 0; r < 16; ++r) {
        c2 p1 = shflx2(s[r], M1);
        c2 p2 = shflx2(s[r], M2);
        c2 p3 = shflx2(s[r], M1 | M2);
        c2 t = cmul2(wS, s[r]);
        t = cfma2(w1, p1, t);
        t = cfma2(w2, p2, t);
        s[r] = cfma2(w3, p3, t);
    }
}

// TWO=true: specialized nlayers==2 path. __launch_bounds__(512,2): one
// 8-wave block/CU = 2 waves/EU -> allocator may use up to 256 VGPRs, no
// scratch spills (round-6 counters showed 11 MB/dispatch spill writeback
// at the default 128-VGPR cap).
template<bool TWO>
__global__ __launch_bounds__(BLK, 2) void qlc_kernel(
    const float* __restrict__ h, const float* __restrict__ enc_w,
    const float* __restrict__ enc_b, const float* __restrict__ qw,
    const float* __restrict__ dec_w, const float* __restrict__ alpha,
    float* __restrict__ out, int nlayers)
{
    const int n = blockIdx.x, tid = threadIdx.x, lane = tid & 63, wv = tid >> 6;
    __shared__ c2 plane[8192];            // 64 KB; multi-purpose
    float* smem = (float*)plane;
    float* vec  = smem;                   // [13*4]  per-wire 2-vectors (by logical bit)
    float* mats = smem + 64;              // [13*8]  layer-1 gate matrices (by wire)
    c2 s[16];

    // ---------------- Epilogue prefetch (hide HBM latency) ------------------
    const size_t rowoff = (size_t)n * NH;
    float h0 = h[rowoff + tid];
    float h1 = (tid < NH - 512) ? h[rowoff + 512 + tid] : 0.f;
    float dw = dec_w[tid & 63];
    float al = alpha[0];

    // ---------------- Phase 1: product state, ONE round ---------------------
    // Half-wave hw (32 lanes, float2 loads) handles wire hw; all 13 wires
    // in parallel (was 2 serial rounds of 8). Wave 7 (hw 14/15, idle)
    // builds the layer-1 gate matrices.
    {
        const int hw = tid >> 5, sl = tid & 31;
        if (hw < P) {
            const int p = hw;
            float2 hv2 = *(const float2*)&h[rowoff + p * 64 + 2 * sl];
            float2 e0  = *(const float2*)&enc_w[       2 * sl];
            float2 e1  = *(const float2*)&enc_w[ 64 +  2 * sl];
            float2 e2  = *(const float2*)&enc_w[128 +  2 * sl];
            float a0 = fmaf(hv2.x, e0.x, hv2.y * e0.y);
            float a1 = fmaf(hv2.x, e1.x, hv2.y * e1.y);
            float a2 = fmaf(hv2.x, e2.x, hv2.y * e2.y);
#pragma unroll
            for (int m = 16; m; m >>= 1) {   // masks <32: stays in half-wave
                a0 += __shfl_xor(a0, m, 64);
                a1 += __shfl_xor(a1, m, 64);
                a2 += __shfl_xor(a2, m, 64);
            }
            float x = 0.5f * (a0 + enc_b[0]), y = 0.5f * (a1 + enc_b[1]), z = 0.5f * (a2 + enc_b[2]);
            float sx, cx, sy, cy, sz, cz;
            __sincosf(x, &sx, &cx); __sincosf(y, &sy, &cy); __sincosf(z, &sz, &cz);
            c2 em = {cz, -sz}, ep = {cz, sz};
            c2 u0 = cmul2(em, make_float2(cy * cx,  sy * sx));   // col0 of RZ*RY*RX
            c2 u1 = cmul2(ep, make_float2(sy * cx, -cy * sx));
            c2 w0 = u0, w1 = u1;
            if (TWO || nlayers > 0) {
                c2 u[4]; const float* q = qw + p * 3;            // layer 0
                build_V(q[0], q[1], q[2], u);
                w0 = cfma2(u[0], u0, cmul2(u[1], u1));
                w1 = cfma2(u[2], u0, cmul2(u[3], u1));
            }
            if (sl == 0) {
                int b = 12 - p;
                vec[b*4+0] = w0.x; vec[b*4+1] = w0.y; vec[b*4+2] = w1.x; vec[b*4+3] = w1.y;
            }
        } else if (TWO && wv == 7 && lane < P) {                 // layer-1 matrices
            c2 u[4]; const float* q = qw + (P + lane) * 3;
            build_V(q[0], q[1], q[2], u);
            float* m = mats + lane * 8;
            m[0]=u[0].x; m[1]=u[0].y; m[2]=u[1].x; m[3]=u[1].y;
            m[4]=u[2].x; m[5]=u[2].y; m[6]=u[3].x; m[7]=u[3].y;
        }
    }
    __syncthreads();

    // Expansion: s[p] = prod_b vec[b][parity(R0[b]&p)]
    {
        c2 pref = {1.f, 0.f};
        const int UB[8] = {0, 6, 7, 8, 9, 10, 11, 12};       // r-independent bits
#pragma unroll
        for (int k = 0; k < 8; ++k) {
            const int b = UB[k];
            int t = __popc(tid & (R0c.r[b] >> 4)) & 1;
            c2 vv = { vec[b*4 + t*2], vec[b*4 + t*2 + 1] };
            pref = cmul2(pref, vv);
        }
        int t1 = (tid >> 7) & 1, t5 = tid & 1;               // R0[1]>>4=0x80, R0[5]>>4=1
        c2 w1v[2] = { {vec[4+t1*2], vec[5+t1*2]}, {vec[4+(t1^1)*2], vec[5+(t1^1)*2]} };
        c2 w2v[2] = { {vec[8],  vec[9]},  {vec[10], vec[11]} };
        c2 w3v[2] = { {vec[12], vec[13]}, {vec[14], vec[15]} };
        c2 w4v[2] = { {vec[16], vec[17]}, {vec[18], vec[19]} };
        c2 w5v[2] = { {vec[20+t5*2], vec[21+t5*2]}, {vec[20+(t5^1)*2], vec[21+(t5^1)*2]} };
        c2 v12[4], v34[4], P5[2];
        v12[0]=cmul2(w1v[0],w2v[0]); v12[1]=cmul2(w1v[0],w2v[1]);
        v12[2]=cmul2(w1v[1],w2v[0]); v12[3]=cmul2(w1v[1],w2v[1]);
        v34[0]=cmul2(w3v[0],w4v[0]); v34[1]=cmul2(w3v[0],w4v[1]);
        v34[2]=cmul2(w3v[1],w4v[0]); v34[3]=cmul2(w3v[1],w4v[1]);
        P5[0]=cmul2(pref,w5v[0]); P5[1]=cmul2(pref,w5v[1]);
#pragma unroll
        for (int r = 0; r < 16; ++r) {
            const int i12 = ((r & 1) << 1) | ((r ^ (r >> 1)) & 1);
            const int i34 = ((((r >> 1) ^ (r >> 2)) & 1) << 1) | (((r >> 2) ^ (r >> 3)) & 1);
            s[r] = cmul2(P5[(r >> 3) & 1], cmul2(v12[i12], v34[i34]));
        }
    }

    unsigned mrows[13];

    if (TWO) {
        // chain 1 is free (frame change). Layer-1 gates, all single-bit masks:
        gate_reg<0>(s, mats + 10*8);     // b=2  <- wire 10
        gate_reg<1>(s, mats +  9*8);     // b=3
        gate_reg<2>(s, mats +  8*8);     // b=4
        gate_reg<3>(s, mats +  7*8);     // b=5
        gate_lane2<1,  2>(s, mats + 6*8, mats + 5*8, lane);  // b=6,7
        gate_lane2<4,  8>(s, mats + 4*8, mats + 3*8, lane);  // b=8,9
        gate_lane2<16,32>(s, mats + 2*8, mats + 1*8, lane);  // b=10,11
        __syncthreads();                 // vec/mats reads done before staging
        // trip 1: fused pair on tid bits 6,7 (tx 64,128). Matrices rebuilt
        // HERE (wave-uniform qw loads) so nothing is held across staging.
#pragma unroll
        for (int r = 0; r < 16; ++r) plane[r*512 + tid] = s[r];
        {
            c2 uA[4], uB[4];
            const float* qA = qw + (P + 12) * 3;   // b=0  <- wire 12, tx=64
            const float* qB = qw + (P + 11) * 3;   // b=1  <- wire 11, tx=128
            build_V(qA[0], qA[1], qA[2], uA);
            build_V(qB[0], qB[1], qB[2], uB);
            int a = (tid >> 6) & 1, b = (tid >> 7) & 1;
            c2 Ud = a ? uA[3] : uA[0], Uo = a ? uA[2] : uA[1];
            c2 Vd = b ? uB[3] : uB[0], Vo = b ? uB[2] : uB[1];
            c2 wS = cmul2(Ud, Vd), w1 = cmul2(Uo, Vd), w2 = cmul2(Ud, Vo), w3 = cmul2(Uo, Vo);
            int p1 = tid ^ 64, p2 = tid ^ 128, p3 = tid ^ 192;
            __syncthreads();
#pragma unroll
            for (int r = 0; r < 16; ++r) {
                c2 a1 = plane[r*512 + p1];
                c2 a2 = plane[r*512 + p2];
                c2 a3 = plane[r*512 + p3];
                c2 t = cmul2(wS, s[r]);
                t = cfma2(w1, a1, t);
                t = cfma2(w2, a2, t);
                s[r] = cfma2(w3, a3, t);
            }
        }
        __syncthreads();
        // trip 2: bit 8 (tx 256)
#pragma unroll
        for (int r = 0; r < 16; ++r) plane[r*512 + tid] = s[r];
        {
            c2 uC[4];
            const float* qC = qw + (P + 0) * 3;    // b=12 <- wire 0, tx=256
            build_V(qC[0], qC[1], qC[2], uC);
            int mb = (tid >> 8) & 1;
            c2 ua = mb ? uC[3] : uC[0], ub = mb ? uC[2] : uC[1];
            int pt = tid ^ 256;
            __syncthreads();
#pragma unroll
            for (int r = 0; r < 16; ++r) {
                c2 pv = plane[r*512 + pt];
                s[r] = cfma2(ua, s[r], cmul2(ub, pv));
            }
        }
        // chain 2 free; measurement rows are compile-time:
#pragma unroll
        for (int b = 0; b < 13; ++b) mrows[b] = F2c.r[b];
    } else {
        // -------- generic fallback (any nlayers != 2): staged gates --------
        unsigned rowF[13], colG[13];
#pragma unroll
        for (int b = 0; b < 13; ++b) { rowF[b] = R0c.r[b]; colG[b] = G0c.r[b]; }
        for (int l = 1; l < nlayers; ++l) {
#pragma unroll
            for (int i = 0; i < P; ++i) { int bc = 12-i, bt = (i==12)?12:(11-i); rowF[bt]^=rowF[bc]; colG[bc]^=colG[bt]; }
#pragma unroll
            for (int b = 0; b < 13; ++b) {
                const float* q = qw + ((size_t)l * P + (12 - b)) * 3;
                c2 u[4]; build_V(q[0], q[1], q[2], u);
                __syncthreads();
#pragma unroll
                for (int r = 0; r < 16; ++r) plane[r*512 + tid] = s[r];
                __syncthreads();
                unsigned m = colG[b], row = rowF[b];
                int pt = tid ^ (int)(m >> 4);
                unsigned mr = m & 15, rl = row & 15;
                int bt_ = __popc(tid & (row >> 4)) & 1;
#pragma unroll
                for (int r = 0; r < 16; ++r) {
                    c2 pv = plane[((r ^ mr) & 15) * 512 + pt];
                    int beta = bt_ ^ (__popc(r & rl) & 1);
                    c2 ua = beta ? u[3] : u[0], ub = beta ? u[2] : u[1];
                    s[r] = cfma2(ua, s[r], cmul2(ub, pv));
                }
            }
        }
        if (nlayers >= 1) {
#pragma unroll
            for (int i = 0; i < P; ++i) { int bc = 12-i, bt = (i==12)?12:(11-i); rowF[bt]^=rowF[bc]; colG[bc]^=colG[bt]; }
        }
#pragma unroll
        for (int b = 0; b < 13; ++b) mrows[b] = rowF[b];
    }

    // ---------------- Measure <Z_w> + decode --------------------------------
    float pr[16];
#pragma unroll
    for (int r = 0; r < 16; ++r) pr[r] = fmaf(s[r].x, s[r].x, s[r].y * s[r].y);
    float ev[13];
#pragma unroll
    for (int b = 0; b < 13; ++b) {
        unsigned row = mrows[b];
        int tp = __popc(tid & (row >> 4)) & 1;
        float acc = 0.f;
#pragma unroll
        for (int r = 0; r < 16; ++r)
            acc += (__popc((unsigned)r & row) & 1) ? -pr[r] : pr[r];
        ev[12 - b] = tp ? -acc : acc;    // wire w = 12-b
    }
#pragma unroll
    for (int w = 0; w < 13; ++w) {
#pragma unroll
        for (int m = 32; m; m >>= 1) ev[w] += __shfl_xor(ev[w], m, 64);
    }
    float* red  = smem + 256;
    float* red2 = smem + 384;
    __syncthreads();                     // all plane reads done; reuse LDS
    if (lane == 0) {
#pragma unroll
        for (int w = 0; w < 13; ++w) red[wv * 13 + w] = ev[w];
    }
    __syncthreads();
    if (tid < 13) {
        float sum = 0.f;
        for (int q = 0; q < 8; ++q) sum += red[q * 13 + tid];
        red2[tid] = sum;
    }
    __syncthreads();
    out[rowoff + tid] = fmaf(al * red2[wv], dw, h0);
    if (tid < NH - 512)
        out[rowoff + 512 + tid] = fmaf(al * red2[wv + 8], dw, h1);
}

extern "C" void kernel_launch(void* const* d_in, const int* in_sizes, int n_in,
                              void* d_out, int out_size, void* d_ws, size_t ws_size,
                              hipStream_t stream) {
    const float* h     = (const float*)d_in[0];
    const float* enc_w = (const float*)d_in[1];
    const float* enc_b = (const float*)d_in[2];
    const float* qw    = (const float*)d_in[3];
    const float* dec_w = (const float*)d_in[4];
    const float* alpha = (const float*)d_in[5];
    float* out = (float*)d_out;

    int N = in_sizes[0] / NH;          // B*T samples
    int L = in_sizes[3] / (P * 3);     // variational layers

    if (L == 2)
        qlc_kernel<true><<<N, BLK, 0, stream>>>(h, enc_w, enc_b, qw, dec_w, alpha, out, L);
    else
        qlc_kernel<false><<<N, BLK, 0, stream>>>(h, enc_w, enc_b, qw, dec_w, alpha, out, L);
}